// Round 7
// baseline (1002.909 us; speedup 1.0000x reference)
//
#include <hip/hip_runtime.h>

#define N 8192
#define EPS 1e-5f

#define TR 64          // rows per tile
#define TC 256         // cols per tile
#define RPW 16         // rows per wave (4 waves/block)
#define CAPW 512       // per-wave LDS edge buffer entries
#define SEG_W 4096     // worst-case edges per wave segment (RPW*TC)
#define NTILES 2112    // active upper-tri tiles (32 col-stripes)
#define NSEG (NTILES * 4)
#define GRID 1024      // co-resident: 4 blocks/CU x 256 CUs
#define NLEAF 64
#define QUOTA (GRID / NLEAF)   // 16 blocks per leaf counter

// ws layout (bytes):
//   [0]     gen (u32)            -- barrier generation (memset 0 each call)
//   [64]    cnt2 (u32)           -- barrier level-2 counter
//   [128]   cnt1[64] stride 64B  -- barrier leaf counters
//   [4352]  deg   float[N]
//   [37120] partial double[GRID]
//   [45312] scnt  u32[NSEG]
//   [79104] edges u32[NSEG*SEG_W]   total ~138.5 MB
static const size_t OFF_GEN  = 0;
static const size_t OFF_CNT2 = 64;
static const size_t OFF_CNT1 = 128;
static const size_t MEMSET_BYTES = 4352;
static const size_t OFF_DEG  = 4352;
static const size_t OFF_PART = OFF_DEG + (size_t)N * 4;        // 37120
static const size_t OFF_SCNT = OFF_PART + (size_t)GRID * 8;    // 45312
static const size_t OFF_EDG  = OFF_SCNT + (size_t)NSEG * 4;    // 79104
static const size_t WS_NEED  = OFF_EDG + (size_t)NSEG * SEG_W * 4;

__device__ __forceinline__ unsigned mbcnt64(unsigned long long m) {
    return __builtin_amdgcn_mbcnt_hi((unsigned)(m >> 32),
           __builtin_amdgcn_mbcnt_lo((unsigned)m, 0u));
}

// Two-level grid barrier: 1024 blocks -> 64 leaf counters (16 each) -> cnt2
// -> gen release. Waiters poll gen with device-scope LOADS (no RMW convoy).
// Requires all GRID blocks co-resident (enforced by launch_bounds + grid size).
__device__ __forceinline__ void grid_barrier(unsigned* gen, unsigned* cnt2,
                                             unsigned* cnt1) {
    __syncthreads();
    __threadfence();                       // release: flush this block's writes
    if (threadIdx.x == 0) {
        const unsigned g = __hip_atomic_load(gen, __ATOMIC_RELAXED,
                                             __HIP_MEMORY_SCOPE_AGENT);
        const unsigned leaf = blockIdx.x & (NLEAF - 1);
        const unsigned a = __hip_atomic_fetch_add(&cnt1[leaf * 16], 1u,
                               __ATOMIC_ACQ_REL, __HIP_MEMORY_SCOPE_AGENT);
        bool released = false;
        if (a + 1u == (unsigned)QUOTA) {
            const unsigned c = __hip_atomic_fetch_add(cnt2, 1u,
                                   __ATOMIC_ACQ_REL, __HIP_MEMORY_SCOPE_AGENT);
            if (c + 1u == (unsigned)NLEAF) {
                for (int i = 0; i < NLEAF; ++i) cnt1[i * 16] = 0u;  // reset for next use
                *cnt2 = 0u;
                __threadfence();
                __hip_atomic_store(gen, g + 1u, __ATOMIC_RELEASE,
                                   __HIP_MEMORY_SCOPE_AGENT);
                released = true;
            }
        }
        if (!released) {
            while (__hip_atomic_load(gen, __ATOMIC_ACQUIRE,
                                     __HIP_MEMORY_SCOPE_AGENT) == g)
                __builtin_amdgcn_s_sleep(8);
        }
        __threadfence();                   // acquire: invalidate stale cache
    }
    __syncthreads();
}

__global__ __launch_bounds__(256, 4) void k_mega(
        const float* __restrict__ g, const float* __restrict__ params,
        float* __restrict__ deg, double* __restrict__ partial,
        unsigned* __restrict__ scnt, unsigned* __restrict__ edges,
        unsigned* __restrict__ gen, unsigned* __restrict__ cnt2,
        unsigned* __restrict__ cnt1, float* __restrict__ out,
        const int segmode) {
    __shared__ float    scol[TC];
    __shared__ unsigned buf[4][CAPW];
    __shared__ double   wsum[4];

    const int tid  = threadIdx.x;
    const int wave = tid >> 6, lane = tid & 63;

    // ---------- phase 0: zero deg ----------
    { const int t = (int)blockIdx.x * 256 + tid; if (t < N) deg[t] = 0.f; }
    grid_barrier(gen, cnt2, cnt1);

    // ---------- phase 1: triangle pass (deg + edge segments) ----------
    for (int aid = (int)blockIdx.x; aid < NTILES; aid += GRID) {
        // decode aid -> (bi, bj): stripe bj<31 holds 4bj+4 tiles starting at
        // S(bj)=2bj^2+2bj; stripe 31 holds 128 starting at 1984.
        int bi, bj;
        if (aid >= 1984) { bj = 31; bi = aid - 1984; }
        else {
            bj = (int)((sqrtf(1.0f + 2.0f * (float)aid) - 1.0f) * 0.5f);
            while (bj > 0 && 2 * bj * bj + 2 * bj > aid) --bj;
            while (bj < 30 && 2 * (bj + 1) * (bj + 1) + 2 * (bj + 1) <= aid) ++bj;
            bi = aid - (2 * bj * bj + 2 * bj);
        }
        const int r0 = bi * TR, c0 = bj * TC;

        scol[tid] = 0.f;
        __syncthreads();

        const int c = c0 + lane * 4;
        const int rbase = r0 + wave * RPW;
        const float* __restrict__ gp = g + (size_t)rbase * N + c;
        unsigned* __restrict__ myseg = edges + ((size_t)aid * 4 + wave) * SEG_W;
        unsigned wc = 0, wflushed = 0;               // wave-uniform registers
        float ca0 = 0.f, ca1 = 0.f, ca2 = 0.f, ca3 = 0.f;

#define EMIT(BB, PRED, OFFv) \
    if (BB) { if (segmode && (PRED)) buf[wave][wc + mbcnt64(BB)] = etag | (OFFv); \
        const unsigned p_ = __popcll(BB); wc += p_; rsum += p_; }

#define FLUSHCHK \
    if (segmode && wc > (unsigned)(CAPW - 256)) { \
        for (unsigned t_ = lane; t_ < wc; t_ += 64) myseg[wflushed + t_] = buf[wave][t_]; \
        wflushed += wc; wc = 0; }

        if (r0 + TR <= c0) {
            #pragma unroll 4
            for (int k = 0; k < RPW; ++k) {
                const float4 v = *reinterpret_cast<const float4*>(gp + (size_t)k * N);
                FLUSHCHK
                ca0 += v.x; ca1 += v.y; ca2 += v.z; ca3 += v.w;
                const unsigned long long b0 = __ballot(v.x != 0.f);
                const unsigned long long b1 = __ballot(v.y != 0.f);
                const unsigned long long b2 = __ballot(v.z != 0.f);
                const unsigned long long b3 = __ballot(v.w != 0.f);
                if (b0 | b1 | b2 | b3) {
                    const int gr = rbase + k;
                    const unsigned etag = ((unsigned)gr << 16) | (unsigned)c;
                    unsigned rsum = 0;
                    EMIT(b0, v.x != 0.f, 0u)
                    EMIT(b1, v.y != 0.f, 1u)
                    EMIT(b2, v.z != 0.f, 2u)
                    EMIT(b3, v.w != 0.f, 3u)
                    if (lane == 0) atomicAdd(&deg[gr], (float)rsum);
                }
            }
        } else {
            for (int k = 0; k < RPW; ++k) {
                const int gr = rbase + k;
                const float4 v = *reinterpret_cast<const float4*>(gp + (size_t)k * N);
                FLUSHCHK
                const bool a0 = (v.x != 0.f) && (c + 0 >= gr);
                const bool a1 = (v.y != 0.f) && (c + 1 >= gr);
                const bool a2 = (v.z != 0.f) && (c + 2 >= gr);
                const bool a3 = (v.w != 0.f) && (c + 3 >= gr);
                ca0 += (c + 0 > gr) ? v.x : 0.f;
                ca1 += (c + 1 > gr) ? v.y : 0.f;
                ca2 += (c + 2 > gr) ? v.z : 0.f;
                ca3 += (c + 3 > gr) ? v.w : 0.f;
                const unsigned long long b0 = __ballot(a0);
                const unsigned long long b1 = __ballot(a1);
                const unsigned long long b2 = __ballot(a2);
                const unsigned long long b3 = __ballot(a3);
                if (b0 | b1 | b2 | b3) {
                    const unsigned etag = ((unsigned)gr << 16) | (unsigned)c;
                    unsigned rsum = 0;
                    EMIT(b0, a0, 0u)
                    EMIT(b1, a1, 1u)
                    EMIT(b2, a2, 2u)
                    EMIT(b3, a3, 3u)
                    if (lane == 0) atomicAdd(&deg[gr], (float)rsum);
                }
            }
        }
#undef EMIT
#undef FLUSHCHK

        if (segmode) {
            for (unsigned t = lane; t < wc; t += 64) myseg[wflushed + t] = buf[wave][t];
            if (lane == 0) scnt[aid * 4 + wave] = wflushed + wc;
        }
        if (ca0 != 0.f) atomicAdd(&scol[lane * 4 + 0], ca0);
        if (ca1 != 0.f) atomicAdd(&scol[lane * 4 + 1], ca1);
        if (ca2 != 0.f) atomicAdd(&scol[lane * 4 + 2], ca2);
        if (ca3 != 0.f) atomicAdd(&scol[lane * 4 + 3], ca3);
        __syncthreads();
        const float sv = scol[tid];
        if (sv != 0.f) atomicAdd(&deg[c0 + tid], sv);
        __syncthreads();                   // scol re-zeroed next tile
    }
    grid_barrier(gen, cnt2, cnt1);

    // ---------- phase 2: likelihood (dense + edge corrections) ----------
    const float alpha = params[0], beta = params[1], sigma = params[2];
    double dlocal = 0.0;

    if (segmode) {
        // dense: 4 balanced row-pairs per block (rows p and N-1-p: N+1 elems)
        #pragma unroll
        for (int q = 0; q < 4; ++q) {
            const int r1 = (int)blockIdx.x + q * GRID;
            const int r2 = N - 1 - r1;
            const float base1 = fmaf(alpha, deg[r1], sigma);
            const float base2 = fmaf(alpha, deg[r2], sigma);
            float local = 0.f;
            for (int j = r1 + tid; j < N; j += 256) {
                const float s = fmaf(beta, deg[j], base1);
                const float p = __fdividef(1.f, 1.f + __expf(s));
                local += __logf(1.f - p + EPS);
            }
            for (int j = r2 + tid; j < N; j += 256) {
                const float s = fmaf(beta, deg[j], base2);
                const float p = __fdividef(1.f, 1.f + __expf(s));
                local += __logf(1.f - p + EPS);
            }
            dlocal += (double)local;
        }
        // edge corrections over compacted segments
        float local = 0.f;
        for (int s = (int)blockIdx.x; s < NSEG; s += GRID) {
            const unsigned n = scnt[s];
            const unsigned* __restrict__ seg = edges + (size_t)s * SEG_W;
            for (unsigned t = tid; t < n; t += 256) {
                const unsigned e = seg[t];
                const float di = deg[e >> 16];
                const float dj = deg[e & 0xffffu];
                const float sc = fmaf(alpha, di, fmaf(beta, dj, sigma));
                const float p = __fdividef(1.f, 1.f + __expf(sc));
                local += __logf(p + EPS) - __logf(1.f - p + EPS);
            }
        }
        dlocal += (double)local;
    } else {
        // tiny-ws fallback: direct upper-tri scan with graph reads
        #pragma unroll
        for (int q = 0; q < 4; ++q) {
            const int r1 = (int)blockIdx.x + q * GRID;
            const int r2 = N - 1 - r1;
            for (int h = 0; h < 2; ++h) {
                const int i = h ? r2 : r1;
                const float base = fmaf(alpha, deg[i], sigma);
                float rl = 0.f;
                for (int j = i + tid; j < N; j += 256) {
                    const float s = fmaf(beta, deg[j], base);
                    const float p = __fdividef(1.f, 1.f + __expf(s));
                    const float gv = g[(size_t)i * N + j];
                    rl += (gv != 0.f) ? __logf(p + EPS) : __logf(1.f - p + EPS);
                }
                dlocal += (double)rl;
            }
        }
    }

    #pragma unroll
    for (int off = 32; off; off >>= 1) dlocal += __shfl_xor(dlocal, off);
    if (lane == 0) wsum[wave] = dlocal;
    __syncthreads();
    if (tid == 0)
        partial[blockIdx.x] = (wsum[0] + wsum[1]) + (wsum[2] + wsum[3]);
    grid_barrier(gen, cnt2, cnt1);

    // ---------- phase 3: block 0 reduces the 1024 partials ----------
    if (blockIdx.x == 0) {
        double s = partial[tid] + partial[tid + 256]
                 + partial[tid + 512] + partial[tid + 768];
        #pragma unroll
        for (int off = 32; off; off >>= 1) s += __shfl_xor(s, off);
        if (lane == 0) wsum[wave] = s;
        __syncthreads();
        if (tid == 0)
            out[0] = (float)(-((wsum[0] + wsum[1]) + (wsum[2] + wsum[3])));
    }
}

extern "C" void kernel_launch(void* const* d_in, const int* in_sizes, int n_in,
                              void* d_out, int out_size, void* d_ws, size_t ws_size,
                              hipStream_t stream) {
    const float* params = (const float*)d_in[0];   // [alpha, beta, sigma]
    const float* graph  = (const float*)d_in[1];   // [N, N] fp32 0/1
    float* out = (float*)d_out;

    char* ws = (char*)d_ws;
    unsigned* gen   = (unsigned*)(ws + OFF_GEN);
    unsigned* cnt2  = (unsigned*)(ws + OFF_CNT2);
    unsigned* cnt1  = (unsigned*)(ws + OFF_CNT1);
    float*    deg   = (float*)(ws + OFF_DEG);
    double*   part  = (double*)(ws + OFF_PART);
    unsigned* scnt  = (unsigned*)(ws + OFF_SCNT);
    unsigned* edges = (unsigned*)(ws + OFF_EDG);
    const int segmode = (ws_size >= WS_NEED) ? 1 : 0;

    hipMemsetAsync(ws, 0, MEMSET_BYTES, stream);   // barrier state only
    k_mega<<<GRID, 256, 0, stream>>>(graph, params, deg, part, scnt, edges,
                                     gen, cnt2, cnt1, out, segmode);
}

// Round 8
// 91.358 us; speedup vs baseline: 10.9778x; 10.9778x over previous
//
#include <hip/hip_runtime.h>

#define N 8192
#define EPS 1e-5f

#define TR 64          // rows per tile
#define TC 256         // cols per tile
#define NBJ 32         // N/TC col-tiles
#define NBI 128        // N/TR row-tiles
#define RPW 16         // rows per wave (4 waves/block)
#define CAPW 512       // per-wave LDS edge buffer entries (flush at >256; max 256/row)
#define SEG_W 4096     // worst-case edges per wave segment (RPW*TC) -> never overflows
#define NTILES 2112    // active upper-tri tiles
#define NSEG (NTILES * 4)
#define NDENSE 4096    // dense pair-blocks
#define NFB 1024       // fallback blocks (tiny-ws path only)

// ws layout (bytes):
//   accv [0,4096)  64 double slots, stride 8 doubles (1/cache line)
//   ovf  [4096]
//   deg  [4224, +32768)
//   cnt  [~37KB, +NSEG*4)
//   edges[..., +NSEG*SEG_W*4)  total ~138 MB
static const size_t OFF_ACC = 0;
static const size_t OFF_OVF = 4096;
static const size_t OFF_DEG = 4224;
static const size_t OFF_CNT = OFF_DEG + (size_t)N * 4;
static const size_t OFF_EDG = OFF_CNT + (size_t)NSEG * 4;
static const size_t WS_NEED = OFF_EDG + (size_t)NSEG * SEG_W * 4;

__device__ __forceinline__ unsigned mbcnt64(unsigned long long m) {
    return __builtin_amdgcn_mbcnt_hi((unsigned)(m >> 32),
           __builtin_amdgcn_mbcnt_lo((unsigned)m, 0u));
}

__global__ void k_init(float* __restrict__ deg, double* __restrict__ accv,
                       unsigned* __restrict__ ovf, const int segmode) {
    const int t = blockIdx.x * 256 + threadIdx.x;
    if (t < 512) accv[t] = 0.0;
    if (t == 513) *ovf = segmode ? 0u : 1u;
    if (t < N) deg[t] = 0.f;
}

// Pass 1: stream the upper triangle once. ALL 16 row-chunks of the wave's
// tile slice are preloaded into registers first (64 VGPR), so 16 global
// loads are in flight before any branchy ballot/EMIT code runs -- the
// data-dependent branches otherwise cap the wave at ~1 outstanding load
// (latency-bound, the round-6 bottleneck hypothesis). Then: row sums via
// popc of ballots; edge compaction via ballot-rank into a per-wave LDS
// buffer (count in a wave-uniform register), coalesced flush to a
// deterministic per-(tile,wave) global segment sized for the worst case.
__global__ __launch_bounds__(256, 4) void k_pass1(const float* __restrict__ g,
        float* __restrict__ deg, unsigned* __restrict__ cnt,
        unsigned* __restrict__ edges, const int segmode) {
    const int bj = (int)blockIdx.x & (NBJ - 1);
    const int bi = (int)blockIdx.x >> 5;
    if (bi > 4 * bj + 3) return;                 // tile fully below diagonal
    const int r0 = bi * TR, c0 = bj * TC;
    const int wave = threadIdx.x >> 6, lane = threadIdx.x & 63;
    const int aid = 2 * bj * (bj + 1) + bi;      // compact active-tile index

    __shared__ float    scol[TC];
    __shared__ unsigned buf[4][CAPW];
    scol[threadIdx.x] = 0.f;
    __syncthreads();

    const int c = c0 + lane * 4;
    const int rbase = r0 + wave * RPW;
    const float* __restrict__ gp = g + (size_t)rbase * N + c;
    unsigned* __restrict__ myseg = edges + ((size_t)aid * 4 + wave) * SEG_W;
    unsigned wc = 0, wflushed = 0;               // wave-uniform registers
    float ca0 = 0.f, ca1 = 0.f, ca2 = 0.f, ca3 = 0.f;

    // ---- batch preload: 16 independent loads issued back-to-back ----
    float4 vv[RPW];
    #pragma unroll
    for (int k = 0; k < RPW; ++k)
        vv[k] = *reinterpret_cast<const float4*>(gp + (size_t)k * N);

#define EMIT(BB, PRED, OFFv) \
    if (BB) { if (segmode && (PRED)) buf[wave][wc + mbcnt64(BB)] = etag | (OFFv); \
        const unsigned p_ = __popcll(BB); wc += p_; rsum += p_; }

#define FLUSHCHK \
    if (segmode && wc > (unsigned)(CAPW - 256)) { \
        for (unsigned t_ = lane; t_ < wc; t_ += 64) myseg[wflushed + t_] = buf[wave][t_]; \
        wflushed += wc; wc = 0; }

    if (r0 + TR <= c0) {
        // strictly-above-diagonal tile: every element is in the triangle
        #pragma unroll
        for (int k = 0; k < RPW; ++k) {
            const float4 v = vv[k];
            FLUSHCHK
            ca0 += v.x; ca1 += v.y; ca2 += v.z; ca3 += v.w;
            const unsigned long long b0 = __ballot(v.x != 0.f);
            const unsigned long long b1 = __ballot(v.y != 0.f);
            const unsigned long long b2 = __ballot(v.z != 0.f);
            const unsigned long long b3 = __ballot(v.w != 0.f);
            if (b0 | b1 | b2 | b3) {
                const int gr = rbase + k;
                const unsigned etag = ((unsigned)gr << 16) | (unsigned)c;
                unsigned rsum = 0;
                EMIT(b0, v.x != 0.f, 0u)
                EMIT(b1, v.y != 0.f, 1u)
                EMIT(b2, v.z != 0.f, 2u)
                EMIT(b3, v.w != 0.f, 3u)
                if (lane == 0) atomicAdd(&deg[gr], (float)rsum);
            }
        }
    } else {
        // diagonal-crossing tile: per-element triangle masks
        #pragma unroll
        for (int k = 0; k < RPW; ++k) {
            const int gr = rbase + k;
            const float4 v = vv[k];
            FLUSHCHK
            const bool a0 = (v.x != 0.f) && (c + 0 >= gr);
            const bool a1 = (v.y != 0.f) && (c + 1 >= gr);
            const bool a2 = (v.z != 0.f) && (c + 2 >= gr);
            const bool a3 = (v.w != 0.f) && (c + 3 >= gr);
            ca0 += (c + 0 > gr) ? v.x : 0.f;
            ca1 += (c + 1 > gr) ? v.y : 0.f;
            ca2 += (c + 2 > gr) ? v.z : 0.f;
            ca3 += (c + 3 > gr) ? v.w : 0.f;
            const unsigned long long b0 = __ballot(a0);
            const unsigned long long b1 = __ballot(a1);
            const unsigned long long b2 = __ballot(a2);
            const unsigned long long b3 = __ballot(a3);
            if (b0 | b1 | b2 | b3) {
                const unsigned etag = ((unsigned)gr << 16) | (unsigned)c;
                unsigned rsum = 0;
                EMIT(b0, a0, 0u)
                EMIT(b1, a1, 1u)
                EMIT(b2, a2, 2u)
                EMIT(b3, a3, 3u)
                if (lane == 0) atomicAdd(&deg[gr], (float)rsum);
            }
        }
    }
#undef EMIT
#undef FLUSHCHK

    if (segmode) {
        for (unsigned t = lane; t < wc; t += 64) myseg[wflushed + t] = buf[wave][t];
        if (lane == 0) cnt[aid * 4 + wave] = wflushed + wc;
    }
    // column (strict-lower counterpart) sums: LDS-combine then one flush
    if (ca0 != 0.f) atomicAdd(&scol[lane * 4 + 0], ca0);
    if (ca1 != 0.f) atomicAdd(&scol[lane * 4 + 1], ca1);
    if (ca2 != 0.f) atomicAdd(&scol[lane * 4 + 2], ca2);
    if (ca3 != 0.f) atomicAdd(&scol[lane * 4 + 3], ca3);
    __syncthreads();
    const float sv = scol[threadIdx.x];
    if (sv != 0.f) atomicAdd(&deg[c0 + threadIdx.x], sv);
}

// Dense S0 (pair-balanced) + edge corrections + (tiny-ws) fallback.
__global__ __launch_bounds__(256) void k_ll(const float* __restrict__ g,
        const float* __restrict__ deg, const float* __restrict__ params,
        const unsigned* __restrict__ cnt, const unsigned* __restrict__ edges,
        const unsigned* __restrict__ ovf, double* __restrict__ accv) {
    const int b = blockIdx.x;
    const unsigned o = *ovf;
    const float alpha = params[0], beta = params[1], sigma = params[2];
    double dlocal = 0.0;

    if (b < NDENSE) {
        if (o) return;
        const int r1 = b, r2 = N - 1 - b;        // pair rows: N+1 iters/block
        const float base1 = fmaf(alpha, deg[r1], sigma);
        const float base2 = fmaf(alpha, deg[r2], sigma);
        float local = 0.f;
        for (int j = r1 + (int)threadIdx.x; j < N; j += 256) {
            const float s = fmaf(beta, deg[j], base1);
            const float p = __fdividef(1.f, 1.f + __expf(s));
            local += __logf(1.f - p + EPS);
        }
        for (int j = r2 + (int)threadIdx.x; j < N; j += 256) {
            const float s = fmaf(beta, deg[j], base2);
            const float p = __fdividef(1.f, 1.f + __expf(s));
            local += __logf(1.f - p + EPS);
        }
        dlocal = (double)local;
    } else if (b < NDENSE + NTILES) {
        if (o) return;
        const int aid = b - NDENSE;
        float local = 0.f;
        for (int w = 0; w < 4; ++w) {
            const unsigned n = cnt[aid * 4 + w];
            const unsigned* __restrict__ seg = edges + ((size_t)aid * 4 + w) * SEG_W;
            for (unsigned t = threadIdx.x; t < n; t += 256) {
                const unsigned e = seg[t];
                const float di = deg[e >> 16];
                const float dj = deg[e & 0xffffu];
                const float s = fmaf(alpha, di, fmaf(beta, dj, sigma));
                const float p = __fdividef(1.f, 1.f + __expf(s));
                local += __logf(p + EPS) - __logf(1.f - p + EPS);
            }
        }
        dlocal = (double)local;
    } else {
        if (!o) return;                          // fallback only when ws tiny
        const int rb = b - NDENSE - NTILES;
        for (int q = 0; q < 8; ++q) {
            const int i = rb * 8 + q;
            const float base = fmaf(alpha, deg[i], sigma);
            float rl = 0.f;
            for (int j = i + (int)threadIdx.x; j < N; j += 256) {
                const float s = fmaf(beta, deg[j], base);
                const float p = __fdividef(1.f, 1.f + __expf(s));
                const float gv = g[(size_t)i * N + j];
                rl += (gv != 0.f) ? __logf(p + EPS) : __logf(1.f - p + EPS);
            }
            dlocal += (double)rl;
        }
    }

    #pragma unroll
    for (int off = 32; off; off >>= 1) dlocal += __shfl_xor(dlocal, off);
    __shared__ double wsum[4];
    const int wv = threadIdx.x >> 6, ln = threadIdx.x & 63;
    if (ln == 0) wsum[wv] = dlocal;
    __syncthreads();
    if (threadIdx.x == 0) {
        const double t = (wsum[0] + wsum[1]) + (wsum[2] + wsum[3]);
        if (t != 0.0) atomicAdd(&accv[(b & 63) * 8], t);   // 64 spread slots
    }
}

__global__ void k_final(const double* __restrict__ accv, float* __restrict__ out) {
    double v = accv[threadIdx.x * 8];
    #pragma unroll
    for (int off = 32; off; off >>= 1) v += __shfl_xor(v, off);
    if (threadIdx.x == 0) out[0] = (float)(-v);
}

extern "C" void kernel_launch(void* const* d_in, const int* in_sizes, int n_in,
                              void* d_out, int out_size, void* d_ws, size_t ws_size,
                              hipStream_t stream) {
    const float* params = (const float*)d_in[0];   // [alpha, beta, sigma]
    const float* graph  = (const float*)d_in[1];   // [N, N] fp32 0/1
    float* out = (float*)d_out;

    char* ws = (char*)d_ws;
    double*   accv  = (double*)(ws + OFF_ACC);
    unsigned* ovf   = (unsigned*)(ws + OFF_OVF);
    float*    deg   = (float*)(ws + OFF_DEG);
    unsigned* cnt   = (unsigned*)(ws + OFF_CNT);
    unsigned* edges = (unsigned*)(ws + OFF_EDG);
    const int segmode = (ws_size >= WS_NEED) ? 1 : 0;

    k_init<<<32, 256, 0, stream>>>(deg, accv, ovf, segmode);
    k_pass1<<<NBI * NBJ, 256, 0, stream>>>(graph, deg, cnt, edges, segmode);
    k_ll<<<NDENSE + NTILES + NFB, 256, 0, stream>>>(graph, deg, params, cnt, edges, ovf, accv);
    k_final<<<1, 64, 0, stream>>>(accv, out);
}